// Round 7
// baseline (511.698 us; speedup 1.0000x reference)
//
#include <hip/hip_runtime.h>
#include <hip/hip_bf16.h>

typedef __bf16 bf16_t;
typedef __attribute__((ext_vector_type(8))) __bf16 bf16x8;
typedef __attribute__((ext_vector_type(4))) float f32x4;

#define MFMA(a, b, c) __builtin_amdgcn_mfma_f32_16x16x32_bf16(a, b, c, 0, 0, 0)

// Async global->LDS, 16B per lane. Dest = wave-uniform base + lane*16 (measured m104).
__device__ inline void gload_lds16(const bf16_t* g, bf16_t* l) {
  __builtin_amdgcn_global_load_lds(
      (const __attribute__((address_space(1))) void*)g,
      (__attribute__((address_space(3))) void*)l, 16, 0, 0);
}

// Diagnostic sentinel (fp32 output): absmax ~= val identifies the guard.
__global__ void fill_sentinel(float* out, int n, float val) {
  int i = blockIdx.x * blockDim.x + threadIdx.x;
  if (i < n) out[i] = val;
}

// Weights fp32 W[h][d][kk] (3 matrices) -> Wt bf16 [m][(h*64+kk)][d]
__global__ void transpose_w(const float* __restrict__ Wq, const float* __restrict__ Wk,
                            const float* __restrict__ Wv, bf16_t* __restrict__ Wt) {
  int gid = blockIdx.x * blockDim.x + threadIdx.x;
  int e = gid * 8;
  int m = e >> 20;
  int rem = e & 1048575;
  int n = rem >> 10;               // h*64+kk
  int d0 = rem & 1023;
  const float* W = (m == 0) ? Wq : (m == 1) ? Wk : Wv;
  int h = n >> 6, kk = n & 63;
  union { bf16_t h8[8]; uint4 u; } tmp;
#pragma unroll
  for (int j = 0; j < 8; ++j)
    tmp.h8[j] = (bf16_t)W[((size_t)(h * 1024 + d0 + j)) * 64 + kk];
  *(uint4*)(Wt + e) = tmp.u;
}

// Vectorized fp32 -> bf16 cast, 8 elems/thread, exact grid (no bounds check).
__global__ void cvt_bf16(const float* __restrict__ in, bf16_t* __restrict__ out) {
  size_t i = (size_t)(blockIdx.x * blockDim.x + threadIdx.x) * 8;
  f32x4 a = *(const f32x4*)(in + i);
  f32x4 b = *(const f32x4*)(in + i + 4);
  bf16x8 r;
  r[0] = (bf16_t)a[0]; r[1] = (bf16_t)a[1]; r[2] = (bf16_t)a[2]; r[3] = (bf16_t)a[3];
  r[4] = (bf16_t)b[0]; r[5] = (bf16_t)b[1]; r[6] = (bf16_t)b[2]; r[7] = (bf16_t)b[3];
  *(bf16x8*)(out + i) = r;
}

// C = A[M,K] * Bt[N,K]^T, all-bf16 inputs. 2-phase double-buffered pipeline
// (UNCHANGED from round 6; neutral vs m97 structure -> keep).
// MODE 0: out bf16 [h][b][s][dk]; MODE 1: out bf16 [h][b][dk][s];
// MODE 2: out fp32 [M,N] + bias.  scale applied in MODE 0/1 epilogue.
template <int MODE>
__global__ void gemm_bt(const bf16_t* __restrict__ A, const bf16_t* __restrict__ Bt,
                        const float* __restrict__ bias, void* __restrict__ out_,
                        int M, int N, int K, float scale) {
  // Linear LDS (global_load_lds requires contiguous dest): 2 bufs x [128 rows][32].
  __shared__ bf16_t sA[2][128 * 32];
  __shared__ bf16_t sB[2][128 * 32];
  const int t = threadIdx.x;
  const int w = t >> 6, l = t & 63;
  const int lq = l >> 4, ll = l & 15;
  const int m0 = blockIdx.x * 128, n0 = blockIdx.y * 128;
  const int wr = (w >> 1) * 64, wc = (w & 1) * 64;
  const int srow = l >> 2;
  const int scol = (l & 3) * 8;
  f32x4 acc[4][4] = {};

  auto stage = [&](int bufi, int k0s) {
#pragma unroll
    for (int c = 0; c < 2; ++c) {
      int ch = w * 2 + c;
      int row = ch * 16 + srow;
      gload_lds16(A  + (size_t)(m0 + row) * K + k0s + scol, sA[bufi] + ch * 512);
      gload_lds16(Bt + (size_t)(n0 + row) * K + k0s + scol, sB[bufi] + ch * 512);
    }
  };

  stage(0, 0);
  __syncthreads();

  int cur = 0;
  for (int k0 = 0; k0 < K; k0 += 32) {
    if (k0 + 32 < K) stage(cur ^ 1, k0 + 32);
    bf16x8 af[4], bfr[4];
#pragma unroll
    for (int i = 0; i < 4; ++i) {
      af[i]  = *(const bf16x8*)(sA[cur] + (wr + i * 16 + ll) * 32 + lq * 8);
      bfr[i] = *(const bf16x8*)(sB[cur] + (wc + i * 16 + ll) * 32 + lq * 8);
    }
#pragma unroll
    for (int mi = 0; mi < 4; ++mi)
#pragma unroll
      for (int ni = 0; ni < 4; ++ni)
        acc[mi][ni] = MFMA(af[mi], bfr[ni], acc[mi][ni]);
    __syncthreads();
    cur ^= 1;
  }
  // D layout: col=lane&15, row=(lane>>4)*4+reg (measured m89/m91).
#pragma unroll
  for (int mi = 0; mi < 4; ++mi)
#pragma unroll
    for (int ni = 0; ni < 4; ++ni)
#pragma unroll
      for (int r = 0; r < 4; ++r) {
        int row = m0 + wr + mi * 16 + lq * 4 + r;
        int col = n0 + wc + ni * 16 + ll;
        float v = acc[mi][ni][r];
        if (MODE == 2) {
          ((float*)out_)[(size_t)row * N + col] = v + bias[col];
        } else {
          int h = col >> 6, kk = col & 63, b = row >> 10, s = row & 1023;
          size_t idx;
          if (MODE == 0)
            idx = ((size_t)((h * 8 + b) * 1024 + s)) * 64 + kk;
          else
            idx = ((size_t)((h * 8 + b) * 64 + kk)) * 1024 + s;
          ((bf16_t*)out_)[idx] = (bf16_t)(v * scale);
        }
      }
}

// Flash attention v6: BARRIER-FREE. qh (PRE-SCALED by 1/8): [h][b][s][dk],
// kh: [h][b][s][dk], vt: [h][b][dk][s], c out: [b][s][h*64+dk].
// Block: 64 q-rows for one (h,b). 4 waves, each owns 16 q-rows.
// v6 rationale: v5 counters (MfmaUtil 9.7 + VALU 24 -> ~65% no-issue with 13
// waves/CU) = all waves stalled together at the 16 per-tile __syncthreads drain
// points. After the T1 swizzle K and V are both L2-resident (256KB/hb, 4MB/XCD)
// so K staging through LDS (whose only purpose was 4x read reuse) costs a
// block-wide barrier per tile for ~nothing. v6 reads K fragments straight from
// global like V -> NO __syncthreads in the loop; sP is per-wave (lgkmcnt only);
// waves run phase-independent so TLP finally hides the per-wave latencies.
// L2 cost: 4x K re-read = +256MB L2 traffic ~ 15us aggregate (34.5 TB/s) - cheap.
// V issued after QK (K frags dead) to cap VGPR; softmax+P round-trip covers V latency.
__global__ void attn_kernel(const bf16_t* __restrict__ qh, const bf16_t* __restrict__ kh,
                            const bf16_t* __restrict__ vt, bf16_t* __restrict__ c) {
  constexpr int PP = 72;
  __shared__ bf16_t sP[4][16 * PP];
  const int t = threadIdx.x;
  const int w = t >> 6, l = t & 63;
  const int lq = l >> 4, ll = l & 15;
  // T1 swizzle: orig = x + 16*y, wg = (orig%8)*256 + orig/8 (bijective, 2048%8==0).
  const int orig = blockIdx.x + (blockIdx.y << 4);
  const int wg = (orig & 7) * 256 + (orig >> 3);
  const int q0 = (wg & 15) * 64;
  const int hb = wg >> 4;             // h*8+b
  const int h = hb >> 3, b = hb & 7;
  const size_t base = (size_t)hb * 65536;
  const bf16_t* Q = qh + base + (size_t)q0 * 64;
  const bf16_t* K = kh + base;
  const bf16_t* V = vt + base;        // [64][1024]

  // Q fragments loop-invariant in regs (B-operand of swapped QK: col=q=ll).
  bf16x8 aq0 = *(const bf16x8*)(Q + (w * 16 + ll) * 64 + 0 * 32 + lq * 8);
  bf16x8 aq1 = *(const bf16x8*)(Q + (w * 16 + ll) * 64 + 1 * 32 + lq * 8);

  float mrow = -1e30f, lrow = 0.f;    // per-lane state for q = w*16+ll
  f32x4 o[4] = {};
  bf16_t* Pw = sP[w];

  for (int kt = 0; kt < 1024; kt += 64) {
    // K fragments straight from global (L2-hot). Row kt+ni*16+ll, col ks*32+lq*8.
    // Per-wave: 16 rows x 64B contiguous per ni -> perfect 64B-line fetches.
    const bf16_t* Kb = K + (size_t)(kt + ll) * 64 + lq * 8;
    bf16x8 bk00 = *(const bf16x8*)(Kb + 0 * 1024 + 0);
    bf16x8 bk01 = *(const bf16x8*)(Kb + 1 * 1024 + 0);
    bf16x8 bk02 = *(const bf16x8*)(Kb + 2 * 1024 + 0);
    bf16x8 bk03 = *(const bf16x8*)(Kb + 3 * 1024 + 0);
    bf16x8 bk10 = *(const bf16x8*)(Kb + 0 * 1024 + 32);
    bf16x8 bk11 = *(const bf16x8*)(Kb + 1 * 1024 + 32);
    bf16x8 bk12 = *(const bf16x8*)(Kb + 2 * 1024 + 32);
    bf16x8 bk13 = *(const bf16x8*)(Kb + 3 * 1024 + 32);

    // Swapped QK^T: S^T[key][q] = MFMA(K-frag, Q-frag).
    f32x4 sacc[4] = {};
    __builtin_amdgcn_s_setprio(1);
    sacc[0] = MFMA(bk00, aq0, sacc[0]);
    sacc[1] = MFMA(bk01, aq0, sacc[1]);
    sacc[2] = MFMA(bk02, aq0, sacc[2]);
    sacc[3] = MFMA(bk03, aq0, sacc[3]);
    sacc[0] = MFMA(bk10, aq1, sacc[0]);
    sacc[1] = MFMA(bk11, aq1, sacc[1]);
    sacc[2] = MFMA(bk12, aq1, sacc[2]);
    sacc[3] = MFMA(bk13, aq1, sacc[3]);
    __builtin_amdgcn_s_setprio(0);

    // V loads issued now (K frags dead): softmax + P round-trip covers L2 latency.
    const bf16_t* Vb = V + (size_t)ll * 1024 + kt + lq * 8;
    bf16x8 bv00 = *(const bf16x8*)(Vb + 0 * 16384 + 0);
    bf16x8 bv01 = *(const bf16x8*)(Vb + 1 * 16384 + 0);
    bf16x8 bv02 = *(const bf16x8*)(Vb + 2 * 16384 + 0);
    bf16x8 bv03 = *(const bf16x8*)(Vb + 3 * 16384 + 0);
    bf16x8 bv10 = *(const bf16x8*)(Vb + 0 * 16384 + 32);
    bf16x8 bv11 = *(const bf16x8*)(Vb + 1 * 16384 + 32);
    bf16x8 bv12 = *(const bf16x8*)(Vb + 2 * 16384 + 32);
    bf16x8 bv13 = *(const bf16x8*)(Vb + 3 * 16384 + 32);

    // Lane-partial max over this lane's 16 keys (all for q = w*16+ll).
    float rmax = -1e30f;
#pragma unroll
    for (int ni = 0; ni < 4; ++ni)
#pragma unroll
      for (int r = 0; r < 4; ++r)
        rmax = fmaxf(rmax, sacc[ni][r]);
    // T13 defer-max: rare rescale only when max grows past THR=8.
    if (!__all(rmax <= mrow + 8.0f)) {
      rmax = fmaxf(rmax, __shfl_xor(rmax, 16));
      rmax = fmaxf(rmax, __shfl_xor(rmax, 32));
      float mnew = fmaxf(mrow, rmax);
      float alpha = __expf(mrow - mnew);
      mrow = mnew;
      lrow *= alpha;
#pragma unroll
      for (int r = 0; r < 4; ++r) {
        float ar = __shfl(alpha, lq * 4 + r, 16);
#pragma unroll
        for (int ni = 0; ni < 4; ++ni)
          o[ni][r] *= ar;
      }
    }
    // P = exp(S - m); lane-partial row sum (scalar, no shuffles).
#pragma unroll
    for (int ni = 0; ni < 4; ++ni)
#pragma unroll
      for (int r = 0; r < 4; ++r) {
        float p = __expf(sacc[ni][r] - mrow);
        sacc[ni][r] = p;
        lrow += p;
      }
    // P-write: consecutive r = consecutive keys -> one 8B packed write per ni.
#pragma unroll
    for (int ni = 0; ni < 4; ++ni) {
      union { bf16_t h4[4]; uint2 u; } pk;
      pk.h4[0] = (bf16_t)sacc[ni][0];
      pk.h4[1] = (bf16_t)sacc[ni][1];
      pk.h4[2] = (bf16_t)sacc[ni][2];
      pk.h4[3] = (bf16_t)sacc[ni][3];
      *(uint2*)(Pw + ll * PP + ni * 16 + lq * 4) = pk.u;
    }
    asm volatile("s_waitcnt lgkmcnt(0)" ::: "memory");
    __builtin_amdgcn_sched_barrier(0);   // rule #18: block MFMA hoist past the wait
    // PV: A = P[q=ll][keys lq*8..+7] (16B ds_read), B = V regs.
    bf16x8 ap0 = *(const bf16x8*)(Pw + ll * PP + 0 * 32 + lq * 8);
    bf16x8 ap1 = *(const bf16x8*)(Pw + ll * PP + 1 * 32 + lq * 8);
    __builtin_amdgcn_s_setprio(1);
    o[0] = MFMA(ap0, bv00, o[0]);
    o[1] = MFMA(ap0, bv01, o[1]);
    o[2] = MFMA(ap0, bv02, o[2]);
    o[3] = MFMA(ap0, bv03, o[3]);
    o[0] = MFMA(ap1, bv10, o[0]);
    o[1] = MFMA(ap1, bv11, o[1]);
    o[2] = MFMA(ap1, bv12, o[2]);
    o[3] = MFMA(ap1, bv13, o[3]);
    __builtin_amdgcn_s_setprio(0);
  }
  // Final: true lrow(q=ll) = sum of 4 lq-group partials; map to o's q = lq*4+r.
  lrow += __shfl_xor(lrow, 16);
  lrow += __shfl_xor(lrow, 32);
#pragma unroll
  for (int r = 0; r < 4; ++r) {
    float lr = __shfl(lrow, lq * 4 + r, 16);
    int s = q0 + w * 16 + lq * 4 + r;
#pragma unroll
    for (int ni = 0; ni < 4; ++ni) {
      int dk = ni * 16 + ll;
      c[((size_t)(b * 1024 + s)) * 1024 + h * 64 + dk] = (bf16_t)(o[ni][r] / lr);
    }
  }
}

extern "C" void kernel_launch(void* const* d_in, const int* in_sizes, int n_in,
                              void* d_out, int out_size, void* d_ws, size_t ws_size,
                              hipStream_t stream) {
  float* out = (float*)d_out;   // reference output dtype is fp32!
  int nblk_out = (out_size + 255) / 256;
  if (n_in != 8) {
    fill_sentinel<<<nblk_out, 256, 0, stream>>>(out, out_size, 600.0f + 10.0f * n_in);
    return;
  }
  const int expect[8] = {8388608, 8388608, 8388608, 1048576,
                         1048576, 1048576, 1048576, 1024};
  for (int i = 0; i < 8; ++i)
    if (in_sizes[i] != expect[i]) {
      fill_sentinel<<<nblk_out, 256, 0, stream>>>(out, out_size, 500.0f + 10.0f * i);
      return;
    }

  // ws map (bf16 elems): qh [0,8M) | kh [8M,16M) | vt [16M,24M) | Wt/cbuf [24M,32M)
  bf16_t* ws   = (bf16_t*)d_ws;
  bf16_t* qhb  = ws;
  bf16_t* khb  = ws + 8388608;
  bf16_t* vtb  = ws + 16777216;
  bf16_t* Wt   = ws + 25165824;
  bf16_t* cbuf = ws + 25165824;   // overlaps Wt (dead after projections)
  bf16_t* Wob  = ws;              // overlaps qhb (dead after attn)
  if (ws_size < 67108864ull) {
    fill_sentinel<<<nblk_out, 256, 0, stream>>>(out, out_size, 400.0f);
    return;
  }

  const float* q  = (const float*)d_in[0];
  const float* k  = (const float*)d_in[1];
  const float* v  = (const float*)d_in[2];
  const float* Wq = (const float*)d_in[3];
  const float* Wk = (const float*)d_in[4];
  const float* Wv = (const float*)d_in[5];
  const float* Wo = (const float*)d_in[6];
  const float* bo = (const float*)d_in[7];

  // d_out (32MB) doubles as bf16 scratch until the final GEMM:
  //   qb [0,8M elems) , kb [8M,16M) ; vb reuses [0,8M) once qb is consumed.
  bf16_t* qb = (bf16_t*)d_out;
  bf16_t* kb = (bf16_t*)d_out + 8388608;
  bf16_t* vb = (bf16_t*)d_out;

  transpose_w<<<1536, 256, 0, stream>>>(Wq, Wk, Wv, Wt);
  cvt_bf16<<<4096, 256, 0, stream>>>(q, qb);
  cvt_bf16<<<4096, 256, 0, stream>>>(k, kb);
  dim3 gg(64, 8);
  // Q projection pre-scaled by 1/sqrt(d_k)=0.125 (exact pow2 in bf16).
  gemm_bt<0><<<gg, 256, 0, stream>>>(qb, Wt,           nullptr, qhb, 8192, 1024, 1024, 0.125f);
  gemm_bt<0><<<gg, 256, 0, stream>>>(kb, Wt + 1048576, nullptr, khb, 8192, 1024, 1024, 1.0f);
  cvt_bf16<<<4096, 256, 0, stream>>>(v, vb);
  gemm_bt<1><<<gg, 256, 0, stream>>>(vb, Wt + 2097152, nullptr, vtb, 8192, 1024, 1024, 1.0f);
  attn_kernel<<<dim3(16, 128), 256, 0, stream>>>(qhb, khb, vtb, cbuf);
  cvt_bf16<<<512, 256, 0, stream>>>(Wo, Wob);
  gemm_bt<2><<<gg, 256, 0, stream>>>(cbuf, Wob, bo, out, 8192, 1024, 1024, 1.0f);
}

// Round 8
// 421.153 us; speedup vs baseline: 1.2150x; 1.2150x over previous
//
#include <hip/hip_runtime.h>
#include <hip/hip_bf16.h>

typedef __bf16 bf16_t;
typedef __attribute__((ext_vector_type(8))) __bf16 bf16x8;
typedef __attribute__((ext_vector_type(4))) float f32x4;

#define MFMA(a, b, c) __builtin_amdgcn_mfma_f32_16x16x32_bf16(a, b, c, 0, 0, 0)

// Async global->LDS, 16B per lane. Dest = wave-uniform base + lane*16 (measured m104).
__device__ inline void gload_lds16(const bf16_t* g, bf16_t* l) {
  __builtin_amdgcn_global_load_lds(
      (const __attribute__((address_space(1))) void*)g,
      (__attribute__((address_space(3))) void*)l, 16, 0, 0);
}

// Diagnostic sentinel (fp32 output): absmax ~= val identifies the guard.
__global__ void fill_sentinel(float* out, int n, float val) {
  int i = blockIdx.x * blockDim.x + threadIdx.x;
  if (i < n) out[i] = val;
}

// Weights fp32 W[h][d][kk] (3 matrices) -> Wt bf16 [m][(h*64+kk)][d]
__global__ void transpose_w(const float* __restrict__ Wq, const float* __restrict__ Wk,
                            const float* __restrict__ Wv, bf16_t* __restrict__ Wt) {
  int gid = blockIdx.x * blockDim.x + threadIdx.x;
  int e = gid * 8;
  int m = e >> 20;
  int rem = e & 1048575;
  int n = rem >> 10;               // h*64+kk
  int d0 = rem & 1023;
  const float* W = (m == 0) ? Wq : (m == 1) ? Wk : Wv;
  int h = n >> 6, kk = n & 63;
  union { bf16_t h8[8]; uint4 u; } tmp;
#pragma unroll
  for (int j = 0; j < 8; ++j)
    tmp.h8[j] = (bf16_t)W[((size_t)(h * 1024 + d0 + j)) * 64 + kk];
  *(uint4*)(Wt + e) = tmp.u;
}

// Vectorized fp32 -> bf16 cast, 8 elems/thread, exact grid (no bounds check).
__global__ void cvt_bf16(const float* __restrict__ in, bf16_t* __restrict__ out) {
  size_t i = (size_t)(blockIdx.x * blockDim.x + threadIdx.x) * 8;
  f32x4 a = *(const f32x4*)(in + i);
  f32x4 b = *(const f32x4*)(in + i + 4);
  bf16x8 r;
  r[0] = (bf16_t)a[0]; r[1] = (bf16_t)a[1]; r[2] = (bf16_t)a[2]; r[3] = (bf16_t)a[3];
  r[4] = (bf16_t)b[0]; r[5] = (bf16_t)b[1]; r[6] = (bf16_t)b[2]; r[7] = (bf16_t)b[3];
  *(bf16x8*)(out + i) = r;
}

// GEMM v7: 64x128 tiles for OCCUPANCY. m102 shape curve maps TF to blocks/CU
// (256blk/1-per-CU=320TF, 1024blk/4-per-CU=833TF); our 128x128 grids were 512blk
// = 2/CU = ~290TF. 64x128 doubles the grid; the fused q+k launch (MODE 0,
// M=16384; qb||kb and qhb||khb are contiguous) reaches 2048blk = 8/CU.
// N=K=1024 hardcoded. 4 waves: wave w owns cols [w*32, w*32+32), all 64 rows.
// acc[4][2], 8 MFMA/K-step. LDS 24KB (2-phase double-buffered, kept from r6).
// MODE 0: fused qk projection -> bf16 [mat][h][b][s][dk], scale 0.125 for q (m0<8192);
// MODE 1: v projection -> bf16 [h][b][dk][s]; MODE 2: fp32 [M,1024] + bias.
template <int MODE>
__global__ void gemm_bt(const bf16_t* __restrict__ A, const bf16_t* __restrict__ Bt_,
                        const float* __restrict__ bias, void* __restrict__ out_) {
  __shared__ bf16_t sA[2][64 * 32];
  __shared__ bf16_t sB[2][128 * 32];
  const int t = threadIdx.x;
  const int w = t >> 6, l = t & 63;
  const int lq = l >> 4, ll = l & 15;
  const int m0 = blockIdx.x * 64, n0 = blockIdx.y * 128;
  // MODE 0: B matrix + scale chosen per block half (rows<8192 = q, else k).
  const bf16_t* Bt = (MODE == 0 && m0 >= 8192) ? Bt_ + 1048576 : Bt_;
  const float scale = (MODE == 0 && m0 < 8192) ? 0.125f : 1.0f;
  const int srow = l >> 2;         // staging: lane -> row (l/4), col (l&3)*8
  const int scol = (l & 3) * 8;
  f32x4 acc[4][2] = {};

  auto stage = [&](int bufi, int k0s) {
    // A: one 16-row chunk per wave (64 rows total).
    gload_lds16(A + (size_t)(m0 + w * 16 + srow) * 1024 + k0s + scol,
                sA[bufi] + w * 512);
    // B: two 16-row chunks per wave (128 rows total).
#pragma unroll
    for (int c = 0; c < 2; ++c) {
      int ch = w * 2 + c;
      gload_lds16(Bt + (size_t)(n0 + ch * 16 + srow) * 1024 + k0s + scol,
                  sB[bufi] + ch * 512);
    }
  };

  stage(0, 0);
  __syncthreads();

  int cur = 0;
  for (int k0 = 0; k0 < 1024; k0 += 32) {
    if (k0 + 32 < 1024) stage(cur ^ 1, k0 + 32);
    bf16x8 af[4], bfr[2];
#pragma unroll
    for (int i = 0; i < 4; ++i)
      af[i] = *(const bf16x8*)(sA[cur] + (i * 16 + ll) * 32 + lq * 8);
#pragma unroll
    for (int i = 0; i < 2; ++i)
      bfr[i] = *(const bf16x8*)(sB[cur] + (w * 32 + i * 16 + ll) * 32 + lq * 8);
#pragma unroll
    for (int mi = 0; mi < 4; ++mi)
#pragma unroll
      for (int ni = 0; ni < 2; ++ni)
        acc[mi][ni] = MFMA(af[mi], bfr[ni], acc[mi][ni]);
    __syncthreads();
    cur ^= 1;
  }
  // D layout: col=lane&15, row=(lane>>4)*4+reg (measured m89/m91).
#pragma unroll
  for (int mi = 0; mi < 4; ++mi)
#pragma unroll
    for (int ni = 0; ni < 2; ++ni)
#pragma unroll
      for (int r = 0; r < 4; ++r) {
        int row = m0 + mi * 16 + lq * 4 + r;
        int col = n0 + w * 32 + ni * 16 + ll;
        float v = acc[mi][ni][r];
        if (MODE == 2) {
          ((float*)out_)[(size_t)row * 1024 + col] = v + bias[col];
        } else if (MODE == 1) {
          int h = col >> 6, kk = col & 63, b = row >> 10, s = row & 1023;
          ((bf16_t*)out_)[((size_t)((h * 8 + b) * 64 + kk)) * 1024 + s] = (bf16_t)v;
        } else {
          int mat = row >> 13, rr = row & 8191;
          int h = col >> 6, kk = col & 63, b = rr >> 10, s = rr & 1023;
          size_t idx = (size_t)mat * 8388608 +
                       ((size_t)((h * 8 + b) * 1024 + s)) * 64 + kk;
          ((bf16_t*)out_)[idx] = (bf16_t)(v * scale);
        }
      }
}

// Flash attention v5 (REVERTED to the round-5/6 proven 141.6us version; the
// round-7 barrier-free variant regressed to 241us -- removing LDS K-staging put
// raw L2 latency + L1 thrash on every wave's critical path. Prefetch-into-LDS
// a full tile ahead is what made v5 fast, not the barrier count per se).
// qh (PRE-SCALED by 1/8): [h][b][s][dk], kh: [h][b][s][dk],
// vt: [h][b][dk][s], c out: [b][s][h*64+dk].
// Block: 64 q-rows for one (h,b). 4 waves, each owns 16 q-rows.
// Swapped QK^T (S^T = MFMA(K,Q)); scalar per-lane m/l state; packed P-writes;
// K double-buffered via NAMED uint4 regs, ONE barrier/tile; V via named regs
// issued before softmax.
__global__ void attn_kernel(const bf16_t* __restrict__ qh, const bf16_t* __restrict__ kh,
                            const bf16_t* __restrict__ vt, bf16_t* __restrict__ c) {
  constexpr int KP = 72, PP = 72;
  __shared__ bf16_t sK[2][64 * KP];
  __shared__ bf16_t sP[4][16 * PP];
  const int t = threadIdx.x;
  const int w = t >> 6, l = t & 63;
  const int lq = l >> 4, ll = l & 15;
  // T1 swizzle: orig = x + 16*y, wg = (orig%8)*256 + orig/8 (bijective, 2048%8==0).
  const int orig = blockIdx.x + (blockIdx.y << 4);
  const int wg = (orig & 7) * 256 + (orig >> 3);
  const int q0 = (wg & 15) * 64;
  const int hb = wg >> 4;             // h*8+b
  const int h = hb >> 3, b = hb & 7;
  const size_t base = (size_t)hb * 65536;
  const bf16_t* Q = qh + base + (size_t)q0 * 64;
  const bf16_t* K = kh + base;
  const bf16_t* V = vt + base;        // [64][1024]

  // Q fragments loop-invariant in regs (B-operand of swapped QK: col=q=ll).
  bf16x8 aq0 = *(const bf16x8*)(Q + (w * 16 + ll) * 64 + 0 * 32 + lq * 8);
  bf16x8 aq1 = *(const bf16x8*)(Q + (w * 16 + ll) * 64 + 1 * 32 + lq * 8);

  // Prologue: stage K tile 0 into sK[0].
  {
    int e0 = t * 8, e1 = (256 + t) * 8;
    uint4 ka = *(const uint4*)(K + e0);
    uint4 kb = *(const uint4*)(K + e1);
    *(uint4*)(sK[0] + (e0 >> 6) * KP + (e0 & 63)) = ka;
    *(uint4*)(sK[0] + (e1 >> 6) * KP + (e1 & 63)) = kb;
  }
  __syncthreads();

  float mrow = -1e30f, lrow = 0.f;    // per-lane state for q = w*16+ll
  f32x4 o[4] = {};
  bf16_t* Pw = sP[w];

  int cur = 0;
  for (int kt = 0; kt < 1024; kt += 64, cur ^= 1) {
    // Prefetch next K tile into named regs (ds_write after PV, before barrier).
    uint4 kr0, kr1;
    if (kt < 960) {
      kr0 = *(const uint4*)(K + (size_t)(kt + 64) * 64 + t * 8);
      kr1 = *(const uint4*)(K + (size_t)(kt + 64) * 64 + (256 + t) * 8);
    }
    // V loads for THIS tile, named (prevents LDS demotion). B-frag: col=dk, k=key.
    const bf16_t* Vb = V + (size_t)ll * 1024 + kt + lq * 8;
    bf16x8 bv00 = *(const bf16x8*)(Vb + 0 * 16384 + 0);
    bf16x8 bv01 = *(const bf16x8*)(Vb + 1 * 16384 + 0);
    bf16x8 bv02 = *(const bf16x8*)(Vb + 2 * 16384 + 0);
    bf16x8 bv03 = *(const bf16x8*)(Vb + 3 * 16384 + 0);
    bf16x8 bv10 = *(const bf16x8*)(Vb + 0 * 16384 + 32);
    bf16x8 bv11 = *(const bf16x8*)(Vb + 1 * 16384 + 32);
    bf16x8 bv12 = *(const bf16x8*)(Vb + 2 * 16384 + 32);
    bf16x8 bv13 = *(const bf16x8*)(Vb + 3 * 16384 + 32);

    // Swapped QK^T: S^T[key][q] = MFMA(K-frag, Q-frag). Same LDS addresses as v3.
    f32x4 sacc[4] = {};
    __builtin_amdgcn_s_setprio(1);
#pragma unroll
    for (int ni = 0; ni < 4; ++ni) {
      bf16x8 bk0 = *(const bf16x8*)(sK[cur] + (ni * 16 + ll) * KP + 0 * 32 + lq * 8);
      bf16x8 bk1 = *(const bf16x8*)(sK[cur] + (ni * 16 + ll) * KP + 1 * 32 + lq * 8);
      sacc[ni] = MFMA(bk0, aq0, sacc[ni]);
      sacc[ni] = MFMA(bk1, aq1, sacc[ni]);
    }
    __builtin_amdgcn_s_setprio(0);
    // Lane-partial max over this lane's 16 keys (all for q = w*16+ll).
    float rmax = -1e30f;
#pragma unroll
    for (int ni = 0; ni < 4; ++ni)
#pragma unroll
      for (int r = 0; r < 4; ++r)
        rmax = fmaxf(rmax, sacc[ni][r]);
    // T13 defer-max: rare rescale only when max grows past THR=8.
    if (!__all(rmax <= mrow + 8.0f)) {
      // True row max: combine the 4 lq-group partials (lanes +-16, +-32).
      rmax = fmaxf(rmax, __shfl_xor(rmax, 16));
      rmax = fmaxf(rmax, __shfl_xor(rmax, 32));
      float mnew = fmaxf(mrow, rmax);
      float alpha = __expf(mrow - mnew);
      mrow = mnew;
      lrow *= alpha;
      // o rows are q = lq*4+r; alpha lives at lane q (per 16-lane segment).
#pragma unroll
      for (int r = 0; r < 4; ++r) {
        float ar = __shfl(alpha, lq * 4 + r, 16);
#pragma unroll
        for (int ni = 0; ni < 4; ++ni)
          o[ni][r] *= ar;
      }
    }
    // P = exp(S - m); lane-partial row sum (scalar, no shuffles).
#pragma unroll
    for (int ni = 0; ni < 4; ++ni)
#pragma unroll
      for (int r = 0; r < 4; ++r) {
        float p = __expf(sacc[ni][r] - mrow);
        sacc[ni][r] = p;
        lrow += p;
      }
    // P-write: consecutive r = consecutive keys -> one 8B packed write per ni.
    // Pw[q=ll][key = ni*16 + lq*4 + r].
#pragma unroll
    for (int ni = 0; ni < 4; ++ni) {
      union { bf16_t h4[4]; uint2 u; } pk;
      pk.h4[0] = (bf16_t)sacc[ni][0];
      pk.h4[1] = (bf16_t)sacc[ni][1];
      pk.h4[2] = (bf16_t)sacc[ni][2];
      pk.h4[3] = (bf16_t)sacc[ni][3];
      *(uint2*)(Pw + ll * PP + ni * 16 + lq * 4) = pk.u;
    }
    asm volatile("s_waitcnt lgkmcnt(0)" ::: "memory");
    __builtin_amdgcn_sched_barrier(0);   // rule #18: block MFMA hoist past the wait
    // PV: A = P[q=ll][keys lq*8..+7] (16B ds_read), B = V (regs, issued early).
    bf16x8 ap0 = *(const bf16x8*)(Pw + ll * PP + 0 * 32 + lq * 8);
    bf16x8 ap1 = *(const bf16x8*)(Pw + ll * PP + 1 * 32 + lq * 8);
    __builtin_amdgcn_s_setprio(1);
    o[0] = MFMA(ap0, bv00, o[0]);
    o[1] = MFMA(ap0, bv01, o[1]);
    o[2] = MFMA(ap0, bv02, o[2]);
    o[3] = MFMA(ap0, bv03, o[3]);
    o[0] = MFMA(ap1, bv10, o[0]);
    o[1] = MFMA(ap1, bv11, o[1]);
    o[2] = MFMA(ap1, bv12, o[2]);
    o[3] = MFMA(ap1, bv13, o[3]);
    __builtin_amdgcn_s_setprio(0);
    // Stage next K tile into alternate buffer; ONE barrier per tile.
    if (kt < 960) {
      int e0 = t * 8, e1 = (256 + t) * 8;
      *(uint4*)(sK[cur ^ 1] + (e0 >> 6) * KP + (e0 & 63)) = kr0;
      *(uint4*)(sK[cur ^ 1] + (e1 >> 6) * KP + (e1 & 63)) = kr1;
    }
    __syncthreads();
  }
  // Final: true lrow(q=ll) = sum of 4 lq-group partials; map to o's q = lq*4+r.
  lrow += __shfl_xor(lrow, 16);
  lrow += __shfl_xor(lrow, 32);
#pragma unroll
  for (int r = 0; r < 4; ++r) {
    float lr = __shfl(lrow, lq * 4 + r, 16);
    int s = q0 + w * 16 + lq * 4 + r;
#pragma unroll
    for (int ni = 0; ni < 4; ++ni) {
      int dk = ni * 16 + ll;
      c[((size_t)(b * 1024 + s)) * 1024 + h * 64 + dk] = (bf16_t)(o[ni][r] / lr);
    }
  }
}

extern "C" void kernel_launch(void* const* d_in, const int* in_sizes, int n_in,
                              void* d_out, int out_size, void* d_ws, size_t ws_size,
                              hipStream_t stream) {
  float* out = (float*)d_out;   // reference output dtype is fp32!
  int nblk_out = (out_size + 255) / 256;
  if (n_in != 8) {
    fill_sentinel<<<nblk_out, 256, 0, stream>>>(out, out_size, 600.0f + 10.0f * n_in);
    return;
  }
  const int expect[8] = {8388608, 8388608, 8388608, 1048576,
                         1048576, 1048576, 1048576, 1024};
  for (int i = 0; i < 8; ++i)
    if (in_sizes[i] != expect[i]) {
      fill_sentinel<<<nblk_out, 256, 0, stream>>>(out, out_size, 500.0f + 10.0f * i);
      return;
    }

  // ws map (bf16 elems): qh [0,8M) | kh [8M,16M) | vt [16M,24M) | Wt/cbuf [24M,32M)
  bf16_t* ws   = (bf16_t*)d_ws;
  bf16_t* qhb  = ws;                  // fused qk out: qh [0,8M) || kh [8M,16M)
  bf16_t* vtb  = ws + 16777216;
  bf16_t* Wt   = ws + 25165824;
  bf16_t* cbuf = ws + 25165824;   // overlaps Wt (dead after projections)
  bf16_t* Wob  = ws;              // overlaps qhb (dead after attn)
  if (ws_size < 67108864ull) {
    fill_sentinel<<<nblk_out, 256, 0, stream>>>(out, out_size, 400.0f);
    return;
  }

  const float* q  = (const float*)d_in[0];
  const float* k  = (const float*)d_in[1];
  const float* v  = (const float*)d_in[2];
  const float* Wq = (const float*)d_in[3];
  const float* Wk = (const float*)d_in[4];
  const float* Wv = (const float*)d_in[5];
  const float* Wo = (const float*)d_in[6];
  const float* bo = (const float*)d_in[7];

  // d_out (32MB) doubles as bf16 scratch until the final GEMM:
  //   qb [0,8M elems) || kb [8M,16M) form one contiguous 16384x1024 A matrix;
  //   vb reuses [0,8M) once the fused qk GEMM has consumed both.
  bf16_t* qb = (bf16_t*)d_out;
  bf16_t* kb = (bf16_t*)d_out + 8388608;
  bf16_t* vb = (bf16_t*)d_out;

  transpose_w<<<1536, 256, 0, stream>>>(Wq, Wk, Wv, Wt);
  cvt_bf16<<<4096, 256, 0, stream>>>(q, qb);
  cvt_bf16<<<4096, 256, 0, stream>>>(k, kb);
  // Fused q+k projection: M=16384, 2048 blocks (8/CU). Scale 0.125 folded for q.
  gemm_bt<0><<<dim3(256, 8), 256, 0, stream>>>(qb, Wt, nullptr, qhb);
  cvt_bf16<<<4096, 256, 0, stream>>>(v, vb);
  gemm_bt<1><<<dim3(128, 8), 256, 0, stream>>>(vb, Wt + 2097152, nullptr, vtb);
  attn_kernel<<<dim3(16, 128), 256, 0, stream>>>(qhb, qhb + 8388608, vtb, cbuf);
  cvt_bf16<<<512, 256, 0, stream>>>(Wo, Wob);
  gemm_bt<2><<<dim3(128, 8), 256, 0, stream>>>(cbuf, Wob, bo, out);
}

// Round 9
// 399.572 us; speedup vs baseline: 1.2806x; 1.0540x over previous
//
#include <hip/hip_runtime.h>
#include <hip/hip_bf16.h>

typedef __bf16 bf16_t;
typedef __attribute__((ext_vector_type(8))) __bf16 bf16x8;
typedef __attribute__((ext_vector_type(4))) float f32x4;

#define MFMA(a, b, c) __builtin_amdgcn_mfma_f32_16x16x32_bf16(a, b, c, 0, 0, 0)

// Async global->LDS, 16B per lane. Dest = wave-uniform base + lane*16 (measured m104).
__device__ inline void gload_lds16(const bf16_t* g, bf16_t* l) {
  __builtin_amdgcn_global_load_lds(
      (const __attribute__((address_space(1))) void*)g,
      (__attribute__((address_space(3))) void*)l, 16, 0, 0);
}

// Diagnostic sentinel (fp32 output): absmax ~= val identifies the guard.
__global__ void fill_sentinel(float* out, int n, float val) {
  int i = blockIdx.x * blockDim.x + threadIdx.x;
  if (i < n) out[i] = val;
}

// Weights fp32 W[h][d][kk] (3 matrices) -> Wt bf16 [m][(h*64+kk)][d]
__global__ void transpose_w(const float* __restrict__ Wq, const float* __restrict__ Wk,
                            const float* __restrict__ Wv, bf16_t* __restrict__ Wt) {
  int gid = blockIdx.x * blockDim.x + threadIdx.x;
  int e = gid * 8;
  int m = e >> 20;
  int rem = e & 1048575;
  int n = rem >> 10;               // h*64+kk
  int d0 = rem & 1023;
  const float* W = (m == 0) ? Wq : (m == 1) ? Wk : Wv;
  int h = n >> 6, kk = n & 63;
  union { bf16_t h8[8]; uint4 u; } tmp;
#pragma unroll
  for (int j = 0; j < 8; ++j)
    tmp.h8[j] = (bf16_t)W[((size_t)(h * 1024 + d0 + j)) * 64 + kk];
  *(uint4*)(Wt + e) = tmp.u;
}

// Vectorized fp32 -> bf16 cast, 8 elems/thread, exact grid (no bounds check).
__global__ void cvt_bf16(const float* __restrict__ in, bf16_t* __restrict__ out) {
  size_t i = (size_t)(blockIdx.x * blockDim.x + threadIdx.x) * 8;
  f32x4 a = *(const f32x4*)(in + i);
  f32x4 b = *(const f32x4*)(in + i + 4);
  bf16x8 r;
  r[0] = (bf16_t)a[0]; r[1] = (bf16_t)a[1]; r[2] = (bf16_t)a[2]; r[3] = (bf16_t)a[3];
  r[4] = (bf16_t)b[0]; r[5] = (bf16_t)b[1]; r[6] = (bf16_t)b[2]; r[7] = (bf16_t)b[3];
  *(bf16x8*)(out + i) = r;
}

// GEMM v8: 128x128 tile + 3-deep counted-vmcnt pipeline (T3+T4, m218 lesson).
// Rounds 6/8 proved: any __syncthreads-per-K-step structure = ~300 TF at these
// shapes because the implicit vmcnt(0) drain exposes the just-issued stage loads
// every step. v8 uses RAW s_barrier (no drain) + s_waitcnt vmcnt(4): buffer k+2
// is staged at the END of step k (post-barrier -> all waves' k-1 reads done,
// race-free); at step k's top we wait only for buf k's 4 loads (issued 2 steps
// ago), leaving 4 newer loads in flight ACROSS the barrier. K=1024 hardcoded;
// tail peeled with vmcnt(0). LDS 48KB -> 3 blocks/CU.
// MODE 0: fused qk projection, A = qb||kb (M=16384): rows<8192 q (scale 0.125),
//         else k -> out bf16 [mat][h][b][s][dk].
// MODE 1: v projection -> bf16 [h][b][dk][s]. MODE 2: fp32 [M,1024] + bias.
template <int MODE>
__global__ void gemm_bt(const bf16_t* __restrict__ A, const bf16_t* __restrict__ Bt_,
                        const float* __restrict__ bias, void* __restrict__ out_) {
  __shared__ bf16_t sA[3][128 * 32];
  __shared__ bf16_t sB[3][128 * 32];
  const int t = threadIdx.x;
  const int w = t >> 6, l = t & 63;
  const int lq = l >> 4, ll = l & 15;
  const int m0 = blockIdx.x * 128, n0 = blockIdx.y * 128;
  const bf16_t* Bt = (MODE == 0 && m0 >= 8192) ? Bt_ + 1048576 : Bt_;
  const float scale = (MODE == 0 && m0 < 8192) ? 0.125f : 1.0f;
  const int wr = (w >> 1) * 64, wc = (w & 1) * 64;
  const int srow = l >> 2;         // staging: lane -> row (l/4), col (l&3)*8
  const int scol = (l & 3) * 8;
  f32x4 acc[4][4] = {};

  // 4 gload_lds16 per thread per stage call (vmcnt += 4).
  auto stage = [&](int bufi, int k0s) {
#pragma unroll
    for (int c = 0; c < 2; ++c) {
      int ch = w * 2 + c;
      int row = ch * 16 + srow;
      gload_lds16(A  + (size_t)(m0 + row) * 1024 + k0s + scol, sA[bufi] + ch * 512);
      gload_lds16(Bt + (size_t)(n0 + row) * 1024 + k0s + scol, sB[bufi] + ch * 512);
    }
  };

  auto compute = [&](int bufi) {
    bf16x8 af[4], bfr[4];
#pragma unroll
    for (int i = 0; i < 4; ++i) {
      af[i]  = *(const bf16x8*)(sA[bufi] + (wr + i * 16 + ll) * 32 + lq * 8);
      bfr[i] = *(const bf16x8*)(sB[bufi] + (wc + i * 16 + ll) * 32 + lq * 8);
    }
#pragma unroll
    for (int mi = 0; mi < 4; ++mi)
#pragma unroll
      for (int ni = 0; ni < 4; ++ni)
        acc[mi][ni] = MFMA(af[mi], bfr[ni], acc[mi][ni]);
  };

  // Prologue: two K-steps in flight (8 outstanding loads).
  stage(0, 0);
  stage(1, 32);

  int cur = 0;
  for (int k0 = 0; k0 < 992; k0 += 32) {
    // Wait ONLY for buf[cur]'s 4 loads (oldest); 4 newer stay in flight.
    asm volatile("s_waitcnt vmcnt(4)" ::: "memory");
    __builtin_amdgcn_s_barrier();          // raw: no vmcnt drain
    __builtin_amdgcn_sched_barrier(0);     // pin: nothing moves above the barrier
    compute(cur);
    __builtin_amdgcn_sched_barrier(0);     // pin: stage stays after the reads
    if (k0 + 64 < 1024) {
      int nb = cur + 2; if (nb >= 3) nb -= 3;
      stage(nb, k0 + 64);                  // overwrites buf read at step k-1: all
    }                                      // waves past this step's barrier -> safe
    ++cur; if (cur == 3) cur = 0;
  }
  // Peeled last step (k0=992): drain everything.
  asm volatile("s_waitcnt vmcnt(0)" ::: "memory");
  __builtin_amdgcn_s_barrier();
  __builtin_amdgcn_sched_barrier(0);
  compute(cur);

  // D layout: col=lane&15, row=(lane>>4)*4+reg (measured m89/m91).
#pragma unroll
  for (int mi = 0; mi < 4; ++mi)
#pragma unroll
    for (int ni = 0; ni < 4; ++ni)
#pragma unroll
      for (int r = 0; r < 4; ++r) {
        int row = m0 + wr + mi * 16 + lq * 4 + r;
        int col = n0 + wc + ni * 16 + ll;
        float v = acc[mi][ni][r];
        if (MODE == 2) {
          ((float*)out_)[(size_t)row * 1024 + col] = v + bias[col];
        } else if (MODE == 1) {
          int h = col >> 6, kk = col & 63, b = row >> 10, s = row & 1023;
          ((bf16_t*)out_)[((size_t)((h * 8 + b) * 64 + kk)) * 1024 + s] = (bf16_t)v;
        } else {
          int mat = row >> 13, rr = row & 8191;
          int h = col >> 6, kk = col & 63, b = rr >> 10, s = rr & 1023;
          size_t idx = (size_t)mat * 8388608 +
                       ((size_t)((h * 8 + b) * 1024 + s)) * 64 + kk;
          ((bf16_t*)out_)[idx] = (bf16_t)(v * scale);
        }
      }
}

// Flash attention v5 (proven 141.6us structure, UNCHANGED - 3rd consecutive
// confirmation at 140.6us). qh (PRE-SCALED by 1/8): [h][b][s][dk],
// kh: [h][b][s][dk], vt: [h][b][dk][s], c out: [b][s][h*64+dk].
// Block: 64 q-rows for one (h,b). 4 waves, each owns 16 q-rows.
// Swapped QK^T (S^T = MFMA(K,Q)); scalar per-lane m/l state; packed P-writes;
// K double-buffered via NAMED uint4 regs, ONE barrier/tile; V via named regs
// issued before softmax.
__global__ void attn_kernel(const bf16_t* __restrict__ qh, const bf16_t* __restrict__ kh,
                            const bf16_t* __restrict__ vt, bf16_t* __restrict__ c) {
  constexpr int KP = 72, PP = 72;
  __shared__ bf16_t sK[2][64 * KP];
  __shared__ bf16_t sP[4][16 * PP];
  const int t = threadIdx.x;
  const int w = t >> 6, l = t & 63;
  const int lq = l >> 4, ll = l & 15;
  // T1 swizzle: orig = x + 16*y, wg = (orig%8)*256 + orig/8 (bijective, 2048%8==0).
  const int orig = blockIdx.x + (blockIdx.y << 4);
  const int wg = (orig & 7) * 256 + (orig >> 3);
  const int q0 = (wg & 15) * 64;
  const int hb = wg >> 4;             // h*8+b
  const int h = hb >> 3, b = hb & 7;
  const size_t base = (size_t)hb * 65536;
  const bf16_t* Q = qh + base + (size_t)q0 * 64;
  const bf16_t* K = kh + base;
  const bf16_t* V = vt + base;        // [64][1024]

  // Q fragments loop-invariant in regs (B-operand of swapped QK: col=q=ll).
  bf16x8 aq0 = *(const bf16x8*)(Q + (w * 16 + ll) * 64 + 0 * 32 + lq * 8);
  bf16x8 aq1 = *(const bf16x8*)(Q + (w * 16 + ll) * 64 + 1 * 32 + lq * 8);

  // Prologue: stage K tile 0 into sK[0].
  {
    int e0 = t * 8, e1 = (256 + t) * 8;
    uint4 ka = *(const uint4*)(K + e0);
    uint4 kb = *(const uint4*)(K + e1);
    *(uint4*)(sK[0] + (e0 >> 6) * KP + (e0 & 63)) = ka;
    *(uint4*)(sK[0] + (e1 >> 6) * KP + (e1 & 63)) = kb;
  }
  __syncthreads();

  float mrow = -1e30f, lrow = 0.f;    // per-lane state for q = w*16+ll
  f32x4 o[4] = {};
  bf16_t* Pw = sP[w];

  int cur = 0;
  for (int kt = 0; kt < 1024; kt += 64, cur ^= 1) {
    // Prefetch next K tile into named regs (ds_write after PV, before barrier).
    uint4 kr0, kr1;
    if (kt < 960) {
      kr0 = *(const uint4*)(K + (size_t)(kt + 64) * 64 + t * 8);
      kr1 = *(const uint4*)(K + (size_t)(kt + 64) * 64 + (256 + t) * 8);
    }
    // V loads for THIS tile, named (prevents LDS demotion). B-frag: col=dk, k=key.
    const bf16_t* Vb = V + (size_t)ll * 1024 + kt + lq * 8;
    bf16x8 bv00 = *(const bf16x8*)(Vb + 0 * 16384 + 0);
    bf16x8 bv01 = *(const bf16x8*)(Vb + 1 * 16384 + 0);
    bf16x8 bv02 = *(const bf16x8*)(Vb + 2 * 16384 + 0);
    bf16x8 bv03 = *(const bf16x8*)(Vb + 3 * 16384 + 0);
    bf16x8 bv10 = *(const bf16x8*)(Vb + 0 * 16384 + 32);
    bf16x8 bv11 = *(const bf16x8*)(Vb + 1 * 16384 + 32);
    bf16x8 bv12 = *(const bf16x8*)(Vb + 2 * 16384 + 32);
    bf16x8 bv13 = *(const bf16x8*)(Vb + 3 * 16384 + 32);

    // Swapped QK^T: S^T[key][q] = MFMA(K-frag, Q-frag). Same LDS addresses as v3.
    f32x4 sacc[4] = {};
    __builtin_amdgcn_s_setprio(1);
#pragma unroll
    for (int ni = 0; ni < 4; ++ni) {
      bf16x8 bk0 = *(const bf16x8*)(sK[cur] + (ni * 16 + ll) * KP + 0 * 32 + lq * 8);
      bf16x8 bk1 = *(const bf16x8*)(sK[cur] + (ni * 16 + ll) * KP + 1 * 32 + lq * 8);
      sacc[ni] = MFMA(bk0, aq0, sacc[ni]);
      sacc[ni] = MFMA(bk1, aq1, sacc[ni]);
    }
    __builtin_amdgcn_s_setprio(0);
    // Lane-partial max over this lane's 16 keys (all for q = w*16+ll).
    float rmax = -1e30f;
#pragma unroll
    for (int ni = 0; ni < 4; ++ni)
#pragma unroll
      for (int r = 0; r < 4; ++r)
        rmax = fmaxf(rmax, sacc[ni][r]);
    // T13 defer-max: rare rescale only when max grows past THR=8.
    if (!__all(rmax <= mrow + 8.0f)) {
      // True row max: combine the 4 lq-group partials (lanes +-16, +-32).
      rmax = fmaxf(rmax, __shfl_xor(rmax, 16));
      rmax = fmaxf(rmax, __shfl_xor(rmax, 32));
      float mnew = fmaxf(mrow, rmax);
      float alpha = __expf(mrow - mnew);
      mrow = mnew;
      lrow *= alpha;
      // o rows are q = lq*4+r; alpha lives at lane q (per 16-lane segment).
#pragma unroll
      for (int r = 0; r < 4; ++r) {
        float ar = __shfl(alpha, lq * 4 + r, 16);
#pragma unroll
        for (int ni = 0; ni < 4; ++ni)
          o[ni][r] *= ar;
      }
    }
    // P = exp(S - m); lane-partial row sum (scalar, no shuffles).
#pragma unroll
    for (int ni = 0; ni < 4; ++ni)
#pragma unroll
      for (int r = 0; r < 4; ++r) {
        float p = __expf(sacc[ni][r] - mrow);
        sacc[ni][r] = p;
        lrow += p;
      }
    // P-write: consecutive r = consecutive keys -> one 8B packed write per ni.
    // Pw[q=ll][key = ni*16 + lq*4 + r].
#pragma unroll
    for (int ni = 0; ni < 4; ++ni) {
      union { bf16_t h4[4]; uint2 u; } pk;
      pk.h4[0] = (bf16_t)sacc[ni][0];
      pk.h4[1] = (bf16_t)sacc[ni][1];
      pk.h4[2] = (bf16_t)sacc[ni][2];
      pk.h4[3] = (bf16_t)sacc[ni][3];
      *(uint2*)(Pw + ll * PP + ni * 16 + lq * 4) = pk.u;
    }
    asm volatile("s_waitcnt lgkmcnt(0)" ::: "memory");
    __builtin_amdgcn_sched_barrier(0);   // rule #18: block MFMA hoist past the wait
    // PV: A = P[q=ll][keys lq*8..+7] (16B ds_read), B = V (regs, issued early).
    bf16x8 ap0 = *(const bf16x8*)(Pw + ll * PP + 0 * 32 + lq * 8);
    bf16x8 ap1 = *(const bf16x8*)(Pw + ll * PP + 1 * 32 + lq * 8);
    __builtin_amdgcn_s_setprio(1);
    o[0] = MFMA(ap0, bv00, o[0]);
    o[1] = MFMA(ap0, bv01, o[1]);
    o[2] = MFMA(ap0, bv02, o[2]);
    o[3] = MFMA(ap0, bv03, o[3]);
    o[0] = MFMA(ap1, bv10, o[0]);
    o[1] = MFMA(ap1, bv11, o[1]);
    o[2] = MFMA(ap1, bv12, o[2]);
    o[3] = MFMA(ap1, bv13, o[3]);
    __builtin_amdgcn_s_setprio(0);
    // Stage next K tile into alternate buffer; ONE barrier per tile.
    if (kt < 960) {
      int e0 = t * 8, e1 = (256 + t) * 8;
      *(uint4*)(sK[cur ^ 1] + (e0 >> 6) * KP + (e0 & 63)) = kr0;
      *(uint4*)(sK[cur ^ 1] + (e1 >> 6) * KP + (e1 & 63)) = kr1;
    }
    __syncthreads();
  }
  // Final: true lrow(q=ll) = sum of 4 lq-group partials; map to o's q = lq*4+r.
  lrow += __shfl_xor(lrow, 16);
  lrow += __shfl_xor(lrow, 32);
#pragma unroll
  for (int r = 0; r < 4; ++r) {
    float lr = __shfl(lrow, lq * 4 + r, 16);
    int s = q0 + w * 16 + lq * 4 + r;
#pragma unroll
    for (int ni = 0; ni < 4; ++ni) {
      int dk = ni * 16 + ll;
      c[((size_t)(b * 1024 + s)) * 1024 + h * 64 + dk] = (bf16_t)(o[ni][r] / lr);
    }
  }
}

extern "C" void kernel_launch(void* const* d_in, const int* in_sizes, int n_in,
                              void* d_out, int out_size, void* d_ws, size_t ws_size,
                              hipStream_t stream) {
  float* out = (float*)d_out;   // reference output dtype is fp32!
  int nblk_out = (out_size + 255) / 256;
  if (n_in != 8) {
    fill_sentinel<<<nblk_out, 256, 0, stream>>>(out, out_size, 600.0f + 10.0f * n_in);
    return;
  }
  const int expect[8] = {8388608, 8388608, 8388608, 1048576,
                         1048576, 1048576, 1048576, 1024};
  for (int i = 0; i < 8; ++i)
    if (in_sizes[i] != expect[i]) {
      fill_sentinel<<<nblk_out, 256, 0, stream>>>(out, out_size, 500.0f + 10.0f * i);
      return;
    }

  // ws map (bf16 elems): qh [0,8M) | kh [8M,16M) | vt [16M,24M) | Wt/cbuf [24M,32M)
  bf16_t* ws   = (bf16_t*)d_ws;
  bf16_t* qhb  = ws;                  // fused qk out: qh [0,8M) || kh [8M,16M)
  bf16_t* vtb  = ws + 16777216;
  bf16_t* Wt   = ws + 25165824;
  bf16_t* cbuf = ws + 25165824;   // overlaps Wt (dead after projections)
  bf16_t* Wob  = ws;              // overlaps qhb (dead after attn)
  if (ws_size < 67108864ull) {
    fill_sentinel<<<nblk_out, 256, 0, stream>>>(out, out_size, 400.0f);
    return;
  }

  const float* q  = (const float*)d_in[0];
  const float* k  = (const float*)d_in[1];
  const float* v  = (const float*)d_in[2];
  const float* Wq = (const float*)d_in[3];
  const float* Wk = (const float*)d_in[4];
  const float* Wv = (const float*)d_in[5];
  const float* Wo = (const float*)d_in[6];
  const float* bo = (const float*)d_in[7];

  // d_out (32MB) doubles as bf16 scratch until the final GEMM:
  //   qb [0,8M elems) || kb [8M,16M) form one contiguous 16384x1024 A matrix;
  //   vb reuses [0,8M) once the fused qk GEMM has consumed both.
  bf16_t* qb = (bf16_t*)d_out;
  bf16_t* kb = (bf16_t*)d_out + 8388608;
  bf16_t* vb = (bf16_t*)d_out;

  transpose_w<<<1536, 256, 0, stream>>>(Wq, Wk, Wv, Wt);
  cvt_bf16<<<4096, 256, 0, stream>>>(q, qb);
  cvt_bf16<<<4096, 256, 0, stream>>>(k, kb);
  // Fused q+k projection: M=16384, 1024 blocks. Scale 0.125 folded for q.
  gemm_bt<0><<<dim3(128, 8), 256, 0, stream>>>(qb, Wt, nullptr, qhb);
  cvt_bf16<<<4096, 256, 0, stream>>>(v, vb);
  gemm_bt<1><<<dim3(64, 8), 256, 0, stream>>>(vb, Wt + 2097152, nullptr, vtb);
  attn_kernel<<<dim3(16, 128), 256, 0, stream>>>(qhb, qhb + 8388608, vtb, cbuf);
  cvt_bf16<<<512, 256, 0, stream>>>(Wo, Wob);
  gemm_bt<2><<<dim3(64, 8), 256, 0, stream>>>(cbuf, Wob, bo, out);
}

// Round 10
// 389.616 us; speedup vs baseline: 1.3133x; 1.0256x over previous
//
#include <hip/hip_runtime.h>
#include <hip/hip_bf16.h>

typedef __bf16 bf16_t;
typedef __attribute__((ext_vector_type(8))) __bf16 bf16x8;
typedef __attribute__((ext_vector_type(4))) float f32x4;

#define MFMA(a, b, c) __builtin_amdgcn_mfma_f32_16x16x32_bf16(a, b, c, 0, 0, 0)

// Async global->LDS, 16B per lane. Dest = wave-uniform base + lane*16 (measured m104).
__device__ inline void gload_lds16(const bf16_t* g, bf16_t* l) {
  __builtin_amdgcn_global_load_lds(
      (const __attribute__((address_space(1))) void*)g,
      (__attribute__((address_space(3))) void*)l, 16, 0, 0);
}

// Diagnostic sentinel (fp32 output): absmax ~= val identifies the guard.
__global__ void fill_sentinel(float* out, int n, float val) {
  int i = blockIdx.x * blockDim.x + threadIdx.x;
  if (i < n) out[i] = val;
}

// Weights fp32 W[h][d][kk] (3 matrices) -> Wt bf16 [m][(h*64+kk)][d]
__global__ void transpose_w(const float* __restrict__ Wq, const float* __restrict__ Wk,
                            const float* __restrict__ Wv, bf16_t* __restrict__ Wt) {
  int gid = blockIdx.x * blockDim.x + threadIdx.x;
  int e = gid * 8;
  int m = e >> 20;
  int rem = e & 1048575;
  int n = rem >> 10;               // h*64+kk
  int d0 = rem & 1023;
  const float* W = (m == 0) ? Wq : (m == 1) ? Wk : Wv;
  int h = n >> 6, kk = n & 63;
  union { bf16_t h8[8]; uint4 u; } tmp;
#pragma unroll
  for (int j = 0; j < 8; ++j)
    tmp.h8[j] = (bf16_t)W[((size_t)(h * 1024 + d0 + j)) * 64 + kk];
  *(uint4*)(Wt + e) = tmp.u;
}

// Vectorized fp32 -> bf16 cast, 8 elems/thread, exact grid (no bounds check).
__global__ void cvt_bf16(const float* __restrict__ in, bf16_t* __restrict__ out) {
  size_t i = (size_t)(blockIdx.x * blockDim.x + threadIdx.x) * 8;
  f32x4 a = *(const f32x4*)(in + i);
  f32x4 b = *(const f32x4*)(in + i + 4);
  bf16x8 r;
  r[0] = (bf16_t)a[0]; r[1] = (bf16_t)a[1]; r[2] = (bf16_t)a[2]; r[3] = (bf16_t)a[3];
  r[4] = (bf16_t)b[0]; r[5] = (bf16_t)b[1]; r[6] = (bf16_t)b[2]; r[7] = (bf16_t)b[3];
  *(bf16x8*)(out + i) = r;
}

// ============================================================================
// gemm_qk256: 256x256-tile 8-wave GEMM for the fused q+k projection (m201-style
// structure: big wave tile + counted vmcnt + LDS XOR swizzle). M=16384, N=1024,
// K=1024 hardcoded -> grid 64x4 = 256 blocks = 1/CU (the template's design pt).
// Wave tile 128x64 (8m x 4n frags). LDS 128KB: [2 buf][2 half][128x64] x {A,B}.
// K-tile = 64. Per tile, 4 phases (quadrant MFMAs) with the stage of tile T+2
// split across the two tail barriers (A-halves after last A-read, B-halves
// after last B-read). One vmcnt(8) gate per tile: at T's gate the 8 newest
// loads are T+1's, so <=8 outstanding guarantees T's 8 loads landed.
// Swizzle (G4 recipe, 128B rows): byte ^= ((row&7)<<4) == elem col-slot(16B)
// cb_phys = cb_logical ^ (row&7). Applied via pre-swizzled global SOURCE for
// global_load_lds (linear dest, rule #21) + swizzled ds_read addresses.
// Output: bf16 [mat][h][b][s][dk]; rows<8192 = q (scale 0.125), else k.
// ============================================================================
__global__ __launch_bounds__(512, 2)
void gemm_qk256(const bf16_t* __restrict__ A, const bf16_t* __restrict__ Bt_,
                bf16_t* __restrict__ out) {
  __shared__ bf16_t sA[2][2][128 * 64];
  __shared__ bf16_t sB[2][2][128 * 64];
  const int t = threadIdx.x;
  const int w = t >> 6, l = t & 63;
  const int lq = l >> 4, ll = l & 15;
  const int wm = w >> 2, wn = w & 3;      // 2 m-waves x 4 n-waves
  const int m0 = blockIdx.x * 256, n0 = blockIdx.y * 256;
  const bf16_t* Bt = (m0 >= 8192) ? Bt_ + 1048576 : Bt_;
  const float scale = (m0 < 8192) ? 0.125f : 1.0f;
  // Staging geometry: per half-tile (128 rows x 64 cols), 2 gloads/thread.
  // gload j: dest elem = j*4096 + t*8 -> row = j*64 + (t>>3), slot (t&7).
  // Pre-swizzled source slot = (t&7) ^ (row&7); row&7 == (t>>3)&7.
  const int rt = t >> 3;                  // 0..63
  const int scol = (((t & 7) ^ (rt & 7)) << 3);
  const int ldsw = w * 512;               // wave-uniform dest component

  f32x4 acc[8][4] = {};

  auto stageHalf = [&](bf16_t* Lh, const bf16_t* Gh) {
#pragma unroll
    for (int j = 0; j < 2; ++j)
      gload_lds16(Gh + (size_t)(j * 64 + rt) * 1024 + scol, Lh + j * 4096 + ldsw);
  };
  auto stageTileA = [&](int buf, int kt) {
    stageHalf(sA[buf][0], A + (size_t)m0 * 1024 + kt * 64);
    stageHalf(sA[buf][1], A + (size_t)(m0 + 128) * 1024 + kt * 64);
  };
  auto stageTileB = [&](int buf, int kt) {
    stageHalf(sB[buf][0], Bt + (size_t)n0 * 1024 + kt * 64);
    stageHalf(sB[buf][1], Bt + (size_t)(n0 + 128) * 1024 + kt * 64);
  };
  // Swizzled fragment read: logical (row, k-slot cb) -> phys col (cb^(row&7))*8.
  auto rdA = [&](const bf16_t* Ah, int row, int cb) {
    return *(const bf16x8*)(Ah + row * 64 + (((cb) ^ (row & 7)) << 3));
  };

  // Prologue: tiles 0 and 1 fully staged (16 loads/thread... 8 per tile-pair).
  stageTileA(0, 0); stageTileB(0, 0);
  stageTileA(1, 1); stageTileB(1, 1);

  const int nb = (wn & 1) * 64;           // wave's n-row base within its B half
  for (int T = 0; T < 16; ++T) {
    const int buf = T & 1;
    if (T == 15) asm volatile("s_waitcnt vmcnt(0)" ::: "memory");
    else         asm volatile("s_waitcnt vmcnt(8)" ::: "memory");
    __builtin_amdgcn_s_barrier();
    __builtin_amdgcn_sched_barrier(0);
    const bf16_t* Ah = sA[buf][wm];
    const bf16_t* Bh = sB[buf][wn >> 1];

    bf16x8 af[4][2], bf[2][2];
    // P1: A quadrant 0 (rows 0-63 of wave half) + B n-frags 0,1.
#pragma unroll
    for (int i = 0; i < 4; ++i)
#pragma unroll
      for (int ks = 0; ks < 2; ++ks)
        af[i][ks] = rdA(Ah, i * 16 + ll, ks * 4 + lq);
#pragma unroll
    for (int n = 0; n < 2; ++n)
#pragma unroll
      for (int ks = 0; ks < 2; ++ks)
        bf[n][ks] = rdA(Bh, nb + n * 16 + ll, ks * 4 + lq);
    __builtin_amdgcn_s_setprio(1);
#pragma unroll
    for (int i = 0; i < 4; ++i)
#pragma unroll
      for (int n = 0; n < 2; ++n)
#pragma unroll
        for (int ks = 0; ks < 2; ++ks)
          acc[i][n] = MFMA(af[i][ks], bf[n][ks], acc[i][n]);
    __builtin_amdgcn_s_setprio(0);
    // P2: B n-frags 2,3 ; MFMA q0 x n23.
#pragma unroll
    for (int n = 0; n < 2; ++n)
#pragma unroll
      for (int ks = 0; ks < 2; ++ks)
        bf[n][ks] = rdA(Bh, nb + (2 + n) * 16 + ll, ks * 4 + lq);
    __builtin_amdgcn_s_setprio(1);
#pragma unroll
    for (int i = 0; i < 4; ++i)
#pragma unroll
      for (int n = 0; n < 2; ++n)
#pragma unroll
        for (int ks = 0; ks < 2; ++ks)
          acc[i][2 + n] = MFMA(af[i][ks], bf[n][ks], acc[i][2 + n]);
    __builtin_amdgcn_s_setprio(0);
    // P3: A quadrant 1 (rows 64-127); MFMA q1 x n23 (reuse bf).
#pragma unroll
    for (int i = 0; i < 4; ++i)
#pragma unroll
      for (int ks = 0; ks < 2; ++ks)
        af[i][ks] = rdA(Ah, 64 + i * 16 + ll, ks * 4 + lq);
    __builtin_amdgcn_s_setprio(1);
#pragma unroll
    for (int i = 0; i < 4; ++i)
#pragma unroll
      for (int n = 0; n < 2; ++n)
#pragma unroll
        for (int ks = 0; ks < 2; ++ks)
          acc[4 + i][2 + n] = MFMA(af[i][ks], bf[n][ks], acc[4 + i][2 + n]);
    __builtin_amdgcn_s_setprio(0);
    // All A reads of tile T done (P3 was the last) -> free A regions.
    asm volatile("s_waitcnt lgkmcnt(0)" ::: "memory");
    __builtin_amdgcn_s_barrier();
    __builtin_amdgcn_sched_barrier(0);
    if (T + 2 < 16) stageTileA(buf, T + 2);
    // P4: B n-frags 0,1 again; MFMA q1 x n01.
#pragma unroll
    for (int n = 0; n < 2; ++n)
#pragma unroll
      for (int ks = 0; ks < 2; ++ks)
        bf[n][ks] = rdA(Bh, nb + n * 16 + ll, ks * 4 + lq);
    __builtin_amdgcn_s_setprio(1);
#pragma unroll
    for (int i = 0; i < 4; ++i)
#pragma unroll
      for (int n = 0; n < 2; ++n)
#pragma unroll
        for (int ks = 0; ks < 2; ++ks)
          acc[4 + i][n] = MFMA(af[i][ks], bf[n][ks], acc[4 + i][n]);
    __builtin_amdgcn_s_setprio(0);
    // All reads of tile T done -> free B regions.
    asm volatile("s_waitcnt lgkmcnt(0)" ::: "memory");
    __builtin_amdgcn_s_barrier();
    __builtin_amdgcn_sched_barrier(0);
    if (T + 2 < 16) stageTileB(buf, T + 2);
  }

  // Epilogue: D layout col=lane&15, row=(lane>>4)*4+reg (measured m89/m91).
#pragma unroll
  for (int mi = 0; mi < 8; ++mi)
#pragma unroll
    for (int ni = 0; ni < 4; ++ni)
#pragma unroll
      for (int r = 0; r < 4; ++r) {
        int row = m0 + wm * 128 + mi * 16 + lq * 4 + r;
        int col = n0 + wn * 64 + ni * 16 + ll;
        float v = acc[mi][ni][r];
        int mat = row >> 13, rr = row & 8191;
        int h = col >> 6, kk = col & 63, b = rr >> 10, s = rr & 1023;
        size_t idx = (size_t)mat * 8388608 +
                     ((size_t)((h * 8 + b) * 1024 + s)) * 64 + kk;
        out[idx] = (bf16_t)(v * scale);
      }
}

// GEMM v8 (kept for v projection + final): 128x128 tile + 3-deep counted-vmcnt
// pipeline. MODE 1: v projection -> bf16 [h][b][dk][s]. MODE 2: fp32 + bias.
template <int MODE>
__global__ void gemm_bt(const bf16_t* __restrict__ A, const bf16_t* __restrict__ Bt_,
                        const float* __restrict__ bias, void* __restrict__ out_) {
  __shared__ bf16_t sA[3][128 * 32];
  __shared__ bf16_t sB[3][128 * 32];
  const int t = threadIdx.x;
  const int w = t >> 6, l = t & 63;
  const int lq = l >> 4, ll = l & 15;
  const int m0 = blockIdx.x * 128, n0 = blockIdx.y * 128;
  const bf16_t* Bt = Bt_;
  const int wr = (w >> 1) * 64, wc = (w & 1) * 64;
  const int srow = l >> 2;
  const int scol = (l & 3) * 8;
  f32x4 acc[4][4] = {};

  auto stage = [&](int bufi, int k0s) {
#pragma unroll
    for (int c = 0; c < 2; ++c) {
      int ch = w * 2 + c;
      int row = ch * 16 + srow;
      gload_lds16(A  + (size_t)(m0 + row) * 1024 + k0s + scol, sA[bufi] + ch * 512);
      gload_lds16(Bt + (size_t)(n0 + row) * 1024 + k0s + scol, sB[bufi] + ch * 512);
    }
  };

  auto compute = [&](int bufi) {
    bf16x8 af[4], bfr[4];
#pragma unroll
    for (int i = 0; i < 4; ++i) {
      af[i]  = *(const bf16x8*)(sA[bufi] + (wr + i * 16 + ll) * 32 + lq * 8);
      bfr[i] = *(const bf16x8*)(sB[bufi] + (wc + i * 16 + ll) * 32 + lq * 8);
    }
#pragma unroll
    for (int mi = 0; mi < 4; ++mi)
#pragma unroll
      for (int ni = 0; ni < 4; ++ni)
        acc[mi][ni] = MFMA(af[mi], bfr[ni], acc[mi][ni]);
  };

  stage(0, 0);
  stage(1, 32);

  int cur = 0;
  for (int k0 = 0; k0 < 992; k0 += 32) {
    asm volatile("s_waitcnt vmcnt(4)" ::: "memory");
    __builtin_amdgcn_s_barrier();
    __builtin_amdgcn_sched_barrier(0);
    compute(cur);
    __builtin_amdgcn_sched_barrier(0);
    if (k0 + 64 < 1024) {
      int nb = cur + 2; if (nb >= 3) nb -= 3;
      stage(nb, k0 + 64);
    }
    ++cur; if (cur == 3) cur = 0;
  }
  asm volatile("s_waitcnt vmcnt(0)" ::: "memory");
  __builtin_amdgcn_s_barrier();
  __builtin_amdgcn_sched_barrier(0);
  compute(cur);

#pragma unroll
  for (int mi = 0; mi < 4; ++mi)
#pragma unroll
    for (int ni = 0; ni < 4; ++ni)
#pragma unroll
      for (int r = 0; r < 4; ++r) {
        int row = m0 + wr + mi * 16 + lq * 4 + r;
        int col = n0 + wc + ni * 16 + ll;
        float v = acc[mi][ni][r];
        if (MODE == 2) {
          ((float*)out_)[(size_t)row * 1024 + col] = v + bias[col];
        } else {
          int h = col >> 6, kk = col & 63, b = row >> 10, s = row & 1023;
          ((bf16_t*)out_)[((size_t)((h * 8 + b) * 64 + kk)) * 1024 + s] = (bf16_t)v;
        }
      }
}

// Flash attention v5 (proven 140.6-141.6us structure, UNCHANGED).
// qh (PRE-SCALED by 1/8): [h][b][s][dk], kh: [h][b][s][dk],
// vt: [h][b][dk][s], c out: [b][s][h*64+dk].
__global__ void attn_kernel(const bf16_t* __restrict__ qh, const bf16_t* __restrict__ kh,
                            const bf16_t* __restrict__ vt, bf16_t* __restrict__ c) {
  constexpr int KP = 72, PP = 72;
  __shared__ bf16_t sK[2][64 * KP];
  __shared__ bf16_t sP[4][16 * PP];
  const int t = threadIdx.x;
  const int w = t >> 6, l = t & 63;
  const int lq = l >> 4, ll = l & 15;
  const int orig = blockIdx.x + (blockIdx.y << 4);
  const int wg = (orig & 7) * 256 + (orig >> 3);
  const int q0 = (wg & 15) * 64;
  const int hb = wg >> 4;
  const int h = hb >> 3, b = hb & 7;
  const size_t base = (size_t)hb * 65536;
  const bf16_t* Q = qh + base + (size_t)q0 * 64;
  const bf16_t* K = kh + base;
  const bf16_t* V = vt + base;

  bf16x8 aq0 = *(const bf16x8*)(Q + (w * 16 + ll) * 64 + 0 * 32 + lq * 8);
  bf16x8 aq1 = *(const bf16x8*)(Q + (w * 16 + ll) * 64 + 1 * 32 + lq * 8);

  {
    int e0 = t * 8, e1 = (256 + t) * 8;
    uint4 ka = *(const uint4*)(K + e0);
    uint4 kb = *(const uint4*)(K + e1);
    *(uint4*)(sK[0] + (e0 >> 6) * KP + (e0 & 63)) = ka;
    *(uint4*)(sK[0] + (e1 >> 6) * KP + (e1 & 63)) = kb;
  }
  __syncthreads();

  float mrow = -1e30f, lrow = 0.f;
  f32x4 o[4] = {};
  bf16_t* Pw = sP[w];

  int cur = 0;
  for (int kt = 0; kt < 1024; kt += 64, cur ^= 1) {
    uint4 kr0, kr1;
    if (kt < 960) {
      kr0 = *(const uint4*)(K + (size_t)(kt + 64) * 64 + t * 8);
      kr1 = *(const uint4*)(K + (size_t)(kt + 64) * 64 + (256 + t) * 8);
    }
    const bf16_t* Vb = V + (size_t)ll * 1024 + kt + lq * 8;
    bf16x8 bv00 = *(const bf16x8*)(Vb + 0 * 16384 + 0);
    bf16x8 bv01 = *(const bf16x8*)(Vb + 1 * 16384 + 0);
    bf16x8 bv02 = *(const bf16x8*)(Vb + 2 * 16384 + 0);
    bf16x8 bv03 = *(const bf16x8*)(Vb + 3 * 16384 + 0);
    bf16x8 bv10 = *(const bf16x8*)(Vb + 0 * 16384 + 32);
    bf16x8 bv11 = *(const bf16x8*)(Vb + 1 * 16384 + 32);
    bf16x8 bv12 = *(const bf16x8*)(Vb + 2 * 16384 + 32);
    bf16x8 bv13 = *(const bf16x8*)(Vb + 3 * 16384 + 32);

    f32x4 sacc[4] = {};
    __builtin_amdgcn_s_setprio(1);
#pragma unroll
    for (int ni = 0; ni < 4; ++ni) {
      bf16x8 bk0 = *(const bf16x8*)(sK[cur] + (ni * 16 + ll) * KP + 0 * 32 + lq * 8);
      bf16x8 bk1 = *(const bf16x8*)(sK[cur] + (ni * 16 + ll) * KP + 1 * 32 + lq * 8);
      sacc[ni] = MFMA(bk0, aq0, sacc[ni]);
      sacc[ni] = MFMA(bk1, aq1, sacc[ni]);
    }
    __builtin_amdgcn_s_setprio(0);
    float rmax = -1e30f;
#pragma unroll
    for (int ni = 0; ni < 4; ++ni)
#pragma unroll
      for (int r = 0; r < 4; ++r)
        rmax = fmaxf(rmax, sacc[ni][r]);
    if (!__all(rmax <= mrow + 8.0f)) {
      rmax = fmaxf(rmax, __shfl_xor(rmax, 16));
      rmax = fmaxf(rmax, __shfl_xor(rmax, 32));
      float mnew = fmaxf(mrow, rmax);
      float alpha = __expf(mrow - mnew);
      mrow = mnew;
      lrow *= alpha;
#pragma unroll
      for (int r = 0; r < 4; ++r) {
        float ar = __shfl(alpha, lq * 4 + r, 16);
#pragma unroll
        for (int ni = 0; ni < 4; ++ni)
          o[ni][r] *= ar;
      }
    }
#pragma unroll
    for (int ni = 0; ni < 4; ++ni)
#pragma unroll
      for (int r = 0; r < 4; ++r) {
        float p = __expf(sacc[ni][r] - mrow);
        sacc[ni][r] = p;
        lrow += p;
      }
#pragma unroll
    for (int ni = 0; ni < 4; ++ni) {
      union { bf16_t h4[4]; uint2 u; } pk;
      pk.h4[0] = (bf16_t)sacc[ni][0];
      pk.h4[1] = (bf16_t)sacc[ni][1];
      pk.h4[2] = (bf16_t)sacc[ni][2];
      pk.h4[3] = (bf16_t)sacc[ni][3];
      *(uint2*)(Pw + ll * PP + ni * 16 + lq * 4) = pk.u;
    }
    asm volatile("s_waitcnt lgkmcnt(0)" ::: "memory");
    __builtin_amdgcn_sched_barrier(0);
    bf16x8 ap0 = *(const bf16x8*)(Pw + ll * PP + 0 * 32 + lq * 8);
    bf16x8 ap1 = *(const bf16x8*)(Pw + ll * PP + 1 * 32 + lq * 8);
    __builtin_amdgcn_s_setprio(1);
    o[0] = MFMA(ap0, bv00, o[0]);
    o[1] = MFMA(ap0, bv01, o[1]);
    o[2] = MFMA(ap0, bv02, o[2]);
    o[3] = MFMA(ap0, bv03, o[3]);
    o[0] = MFMA(ap1, bv10, o[0]);
    o[1] = MFMA(ap1, bv11, o[1]);
    o[2] = MFMA(ap1, bv12, o[2]);
    o[3] = MFMA(ap1, bv13, o[3]);
    __builtin_amdgcn_s_setprio(0);
    if (kt < 960) {
      int e0 = t * 8, e1 = (256 + t) * 8;
      *(uint4*)(sK[cur ^ 1] + (e0 >> 6) * KP + (e0 & 63)) = kr0;
      *(uint4*)(sK[cur ^ 1] + (e1 >> 6) * KP + (e1 & 63)) = kr1;
    }
    __syncthreads();
  }
  lrow += __shfl_xor(lrow, 16);
  lrow += __shfl_xor(lrow, 32);
#pragma unroll
  for (int r = 0; r < 4; ++r) {
    float lr = __shfl(lrow, lq * 4 + r, 16);
    int s = q0 + w * 16 + lq * 4 + r;
#pragma unroll
    for (int ni = 0; ni < 4; ++ni) {
      int dk = ni * 16 + ll;
      c[((size_t)(b * 1024 + s)) * 1024 + h * 64 + dk] = (bf16_t)(o[ni][r] / lr);
    }
  }
}

extern "C" void kernel_launch(void* const* d_in, const int* in_sizes, int n_in,
                              void* d_out, int out_size, void* d_ws, size_t ws_size,
                              hipStream_t stream) {
  float* out = (float*)d_out;   // reference output dtype is fp32!
  int nblk_out = (out_size + 255) / 256;
  if (n_in != 8) {
    fill_sentinel<<<nblk_out, 256, 0, stream>>>(out, out_size, 600.0f + 10.0f * n_in);
    return;
  }
  const int expect[8] = {8388608, 8388608, 8388608, 1048576,
                         1048576, 1048576, 1048576, 1024};
  for (int i = 0; i < 8; ++i)
    if (in_sizes[i] != expect[i]) {
      fill_sentinel<<<nblk_out, 256, 0, stream>>>(out, out_size, 500.0f + 10.0f * i);
      return;
    }

  // ws map (bf16 elems): qh [0,8M) | kh [8M,16M) | vt [16M,24M) | Wt/cbuf [24M,32M)
  bf16_t* ws   = (bf16_t*)d_ws;
  bf16_t* qhb  = ws;                  // fused qk out: qh [0,8M) || kh [8M,16M)
  bf16_t* vtb  = ws + 16777216;
  bf16_t* Wt   = ws + 25165824;
  bf16_t* cbuf = ws + 25165824;   // overlaps Wt (dead after projections)
  bf16_t* Wob  = ws;              // overlaps qhb (dead after attn)
  if (ws_size < 67108864ull) {
    fill_sentinel<<<nblk_out, 256, 0, stream>>>(out, out_size, 400.0f);
    return;
  }

  const float* q  = (const float*)d_in[0];
  const float* k  = (const float*)d_in[1];
  const float* v  = (const float*)d_in[2];
  const float* Wq = (const float*)d_in[3];
  const float* Wk = (const float*)d_in[4];
  const float* Wv = (const float*)d_in[5];
  const float* Wo = (const float*)d_in[6];
  const float* bo = (const float*)d_in[7];

  // d_out (32MB) doubles as bf16 scratch until the final GEMM:
  //   qb [0,8M elems) || kb [8M,16M) form one contiguous 16384x1024 A matrix;
  //   vb reuses [0,8M) once the fused qk GEMM has consumed both.
  bf16_t* qb = (bf16_t*)d_out;
  bf16_t* kb = (bf16_t*)d_out + 8388608;
  bf16_t* vb = (bf16_t*)d_out;

  transpose_w<<<1536, 256, 0, stream>>>(Wq, Wk, Wv, Wt);
  cvt_bf16<<<4096, 256, 0, stream>>>(q, qb);
  cvt_bf16<<<4096, 256, 0, stream>>>(k, kb);
  // Fused q+k projection: 256x256-tile 8-wave kernel, 256 blocks = 1/CU.
  gemm_qk256<<<dim3(64, 4), 512, 0, stream>>>(qb, Wt, qhb);
  cvt_bf16<<<4096, 256, 0, stream>>>(v, vb);
  gemm_bt<1><<<dim3(64, 8), 256, 0, stream>>>(vb, Wt + 2097152, nullptr, vtb);
  attn_kernel<<<dim3(16, 128), 256, 0, stream>>>(qhb, qhb + 8388608, vtb, cbuf);
  cvt_bf16<<<512, 256, 0, stream>>>(Wo, Wob);
  gemm_bt<2><<<dim3(64, 8), 256, 0, stream>>>(cbuf, Wob, bo, out);
}